// Round 2
// baseline (710.887 us; speedup 1.0000x reference)
//
#include <hip/hip_runtime.h>

// Problem constants (z: [4, 64, 32, 32, 32] f32, embedding: [1024, 64] f32)
#define CH     64
#define KC     1024
#define SP     32768              // 32*32*32
#define NBATCH 4
#define NTOK   (NBATCH * SP)      // 131072
#define MTOK   128                // tokens per block (32 per wave)
#define ECH    128                // codes per LDS chunk
#define NCHK   (KC / ECH)         // 8 chunks
#define SZEB   72                 // ebl row stride in shorts (144 B = 9*16): bank-balanced
#define CAP    6                  // candidate slots per token (overflow -> exact scan)
#define MARGIN 3.0f               // > 2*eps, eps = max |d_bf16 - d_fp32| (~0.9)

// d_out flat layout (all float32): z_q, loss, perplexity, indices, mean(dist)
#define OFF_ZQ   0
#define OFF_LOSS (NBATCH * CH * SP)      // 8388608
#define OFF_PERP (OFF_LOSS + 1)
#define OFF_IDX  (OFF_PERP + 1)          // 8388610
#define OFF_MEAN (OFF_IDX + NTOK)        // 8519682

// workspace layout (32-bit words)
// [0,1024)      int   hist
// [1024]        float sum_z2
// [1025]        float sum_e2
// [1026,1090)   float sum_zc[64]
// [1090,1154)   float sum_ec[64]
// [1154,2178)   float enorm[1024]
// [4096,20480)  ushort eb[1024*64]  (bf16 embedding table, 128 KB, L2-resident)

typedef __attribute__((ext_vector_type(8))) short  s16x8;   // 8 bf16 (4 VGPRs)
typedef __attribute__((ext_vector_type(4))) float  f32x4;

__device__ __forceinline__ unsigned short f2bf(float f) {   // RNE, deterministic
    unsigned int u = __float_as_uint(f);
    return (unsigned short)((u + 0x7fffu + ((u >> 16) & 1u)) >> 16);
}

// frozen exact fp32 distance (bitwise identical to prior rounds: stride-4
// fmaf chains ascending j, combine nrm - 2*((a0+a1)+(a2+a3))); zr in registers
__device__ __forceinline__ float exact_dist_r(const float* zr,
                                              const float* __restrict__ emb,
                                              const float* __restrict__ enl, int c) {
    const float4* er = (const float4*)(emb + (size_t)c * CH);
    float a0 = 0.f, a1 = 0.f, a2 = 0.f, a3 = 0.f;
#pragma unroll
    for (int j = 0; j < 16; ++j) {
        float4 e4 = er[j];
        a0 = fmaf(zr[4 * j + 0], e4.x, a0);
        a1 = fmaf(zr[4 * j + 1], e4.y, a1);
        a2 = fmaf(zr[4 * j + 2], e4.z, a2);
        a3 = fmaf(zr[4 * j + 3], e4.w, a3);
    }
    return enl[c] - 2.f * ((a0 + a1) + (a2 + a3));
}

// prep: blocks 0-3 enorm, block 4 col-stats + zero sums, 5-8 zero hist,
// 9-12 fp32->bf16 embedding table.
__global__ __launch_bounds__(256) void prep(const float* __restrict__ e,
                                            int* __restrict__ hist,
                                            float* __restrict__ sums,
                                            float* __restrict__ sum_zc,
                                            float* __restrict__ sum_ec,
                                            float* __restrict__ enorm,
                                            unsigned short* __restrict__ eb) {
    const int tid = threadIdx.x;
    const int bk = blockIdx.x;
    if (bk < 4) {
        int k = bk * 256 + tid;
        const float4* row = (const float4*)(e + (size_t)k * CH);
        float n = 0.f;
#pragma unroll
        for (int j = 0; j < CH / 4; ++j) {
            float4 v = row[j];
            n += v.x * v.x + v.y * v.y + v.z * v.z + v.w * v.w;
        }
        enorm[k] = n;
    } else if (bk == 4) {
        if (tid == 0) sums[0] = 0.f;
        if (tid < 64) sum_zc[tid] = 0.f;
        __shared__ float ls1[256];
        __shared__ float r2[4];
        int c = tid & 63;
        int strip = tid >> 6;
        float s1 = 0.f, s2 = 0.f;
        for (int k = strip * 256; k < strip * 256 + 256; ++k) {
            float v = e[k * CH + c];
            s1 += v;
            s2 = fmaf(v, v, s2);
        }
        ls1[tid] = s1;
        for (int off = 32; off; off >>= 1) s2 += __shfl_down(s2, off);
        if ((tid & 63) == 0) r2[tid >> 6] = s2;
        __syncthreads();
        if (strip == 0) sum_ec[c] = ls1[c] + ls1[64 + c] + ls1[128 + c] + ls1[192 + c];
        if (tid == 0) sums[1] = r2[0] + r2[1] + r2[2] + r2[3];
    } else if (bk < 9) {
        hist[(bk - 5) * 256 + tid] = 0;
    } else {
        int base = (bk - 9) * 16384;
        for (int j = 0; j < 64; ++j) {
            int i = base + tid + j * 256;
            eb[i] = f2bf(e[i]);
        }
    }
}

// A-fragment from global z (channel-major): 8 channels cbase..cbase+7 of token toff
__device__ __forceinline__ s16x8 mk8g(const float* __restrict__ zg, int cbase, int toff) {
    s16x8 A;
#pragma unroll
    for (int j = 0; j < 8; ++j)
        A[j] = (short)f2bf(zg[(size_t)(cbase + j) * SP + toff]);
    return A;
}

// main: MFMA candidate generation with DOUBLE-BUFFERED LDS-staged eb chunks
// (T3-lite pipeline: issue next-chunk loads -> compute current -> ds_write ->
// one barrier). No z LDS tile: fragments/rescore/epilogue/stats read z from
// global (L1/L2-hot, identical values). LDS = 40960 B -> 4 blocks/CU.
__global__ __launch_bounds__(256, 4) void vq_main(const float* __restrict__ z,
                                                  const float* __restrict__ emb,
                                                  const unsigned short* __restrict__ eb,
                                                  const float* __restrict__ enorm,
                                                  float* __restrict__ out,
                                                  int* __restrict__ hist,
                                                  float* __restrict__ sums,
                                                  float* __restrict__ sum_zc) {
    __shared__ __align__(16) unsigned short ebl[2][ECH * SZEB]; // 36864 B
    __shared__ int cand[MTOK][CAP];                             // 3072 B (zs-aliased at tail)
    __shared__ int ccnt[MTOK];                                  // 512 B
    __shared__ int fi[MTOK];                                    // 512 B

    const int tid = threadIdx.x;
    const int w = tid >> 6;             // wave 0..3
    const int lane = tid & 63;
    const int n15 = lane & 15;
    const int q = lane >> 4;            // 0..3
    const int t0 = blockIdx.x * MTOK;   // grid = 1024
    const int bb = t0 >> 15;
    const int s0 = t0 & (SP - 1);
    const float* zG = z + ((size_t)bb * CH) * SP + s0;

    // ---- persistent A fragments straight from global (values == old zl copies) ----
    s16x8 A0, A1, A2, A3;
    {
        int ta = w * 32 + n15, tb2 = ta + 16;
        A0 = mk8g(zG, q * 8, ta);
        A1 = mk8g(zG, 32 + q * 8, ta);
        A2 = mk8g(zG, q * 8, tb2);
        A3 = mk8g(zG, 32 + q * 8, tb2);
    }

    // staging decomposition: thread covers rows r0+{0,32,64,96}, granule j
    const int r0 = tid >> 3, sj = tid & 7;
    float4 g0, g1, g2, g3;
#define STAGE_LOAD(cb)                                                      \
    {                                                                       \
        g0 = ((const float4*)(eb + (size_t)((cb) + r0) * CH))[sj];          \
        g1 = ((const float4*)(eb + (size_t)((cb) + r0 + 32) * CH))[sj];     \
        g2 = ((const float4*)(eb + (size_t)((cb) + r0 + 64) * CH))[sj];     \
        g3 = ((const float4*)(eb + (size_t)((cb) + r0 + 96) * CH))[sj];     \
    }
#define STAGE_WRITE(buf)                                                    \
    {                                                                       \
        ((float4*)&ebl[buf][(r0) * SZEB])[sj] = g0;                         \
        ((float4*)&ebl[buf][(r0 + 32) * SZEB])[sj] = g1;                    \
        ((float4*)&ebl[buf][(r0 + 64) * SZEB])[sj] = g2;                    \
        ((float4*)&ebl[buf][(r0 + 96) * SZEB])[sj] = g3;                    \
    }

    // ---- prologue: stage chunk 0 into buf0 ----
    STAGE_LOAD(0)
    STAGE_WRITE(0)
    if (tid < MTOK) ccnt[tid] = 0;
    __syncthreads();

    float bmin0[4] = {3.4e38f, 3.4e38f, 3.4e38f, 3.4e38f};
    float bmin1[4] = {3.4e38f, 3.4e38f, 3.4e38f, 3.4e38f};
    float thr0[4], thr1[4];
    const int tb0 = w * 32 + 4 * q;      // group-0 tokens: tb0 + r
    const int tb1 = tb0 + 16;            // group-1 tokens

    // chunk sequence: pass 1 = 0..7, pass 2 = 7,0..6 (chunk 7 stays resident)
    const int cseq[16] = {0, 1, 2, 3, 4, 5, 6, 7, 7, 0, 1, 2, 3, 4, 5, 6};
    int cur = 0;

    for (int p = 0; p < 16; ++p) {
        const int cb = cseq[p] * ECH;            // current chunk code base
        const bool have_next = (p != 7) && (p != 15);
        if (have_next) STAGE_LOAD(cseq[p + 1] * ECH)   // in flight during compute

        if (p < 8) {
            // ---- pass 1: per-token min of d_bf ----
#pragma unroll
            for (int ct = 0; ct < 8; ++ct) {
                const unsigned short* pb = &ebl[cur][(ct * 16 + n15) * SZEB + q * 8];
                s16x8 B0 = *(const s16x8*)pb;
                s16x8 B1 = *(const s16x8*)(pb + 32);
                float en = enorm[cb + ct * 16 + n15];
                f32x4 acc0 = {0.f, 0.f, 0.f, 0.f};
                f32x4 acc1 = {0.f, 0.f, 0.f, 0.f};
                acc0 = __builtin_amdgcn_mfma_f32_16x16x32_bf16(A0, B0, acc0, 0, 0, 0);
                acc0 = __builtin_amdgcn_mfma_f32_16x16x32_bf16(A1, B1, acc0, 0, 0, 0);
                acc1 = __builtin_amdgcn_mfma_f32_16x16x32_bf16(A2, B0, acc1, 0, 0, 0);
                acc1 = __builtin_amdgcn_mfma_f32_16x16x32_bf16(A3, B1, acc1, 0, 0, 0);
#pragma unroll
                for (int r = 0; r < 4; ++r) {
                    bmin0[r] = fminf(bmin0[r], fmaf(-2.f, acc0[r], en));
                    bmin1[r] = fminf(bmin1[r], fmaf(-2.f, acc1[r], en));
                }
            }
            if (p == 7) {
                // butterfly over n15: min lands in all 16 lanes of the group;
                // threshold is wave-local -> no LDS, no barrier
#pragma unroll
                for (int off = 1; off < 16; off <<= 1)
#pragma unroll
                    for (int r = 0; r < 4; ++r) {
                        bmin0[r] = fminf(bmin0[r], __shfl_xor(bmin0[r], off));
                        bmin1[r] = fminf(bmin1[r], __shfl_xor(bmin1[r], off));
                    }
#pragma unroll
                for (int r = 0; r < 4; ++r) {
                    thr0[r] = bmin0[r] + MARGIN;
                    thr1[r] = bmin1[r] + MARGIN;
                }
            }
        } else {
            // ---- pass 2: identical compute, collect candidates within margin ----
#pragma unroll
            for (int ct = 0; ct < 8; ++ct) {
                const unsigned short* pb = &ebl[cur][(ct * 16 + n15) * SZEB + q * 8];
                s16x8 B0 = *(const s16x8*)pb;
                s16x8 B1 = *(const s16x8*)(pb + 32);
                float en = enorm[cb + ct * 16 + n15];
                f32x4 acc0 = {0.f, 0.f, 0.f, 0.f};
                f32x4 acc1 = {0.f, 0.f, 0.f, 0.f};
                acc0 = __builtin_amdgcn_mfma_f32_16x16x32_bf16(A0, B0, acc0, 0, 0, 0);
                acc0 = __builtin_amdgcn_mfma_f32_16x16x32_bf16(A1, B1, acc0, 0, 0, 0);
                acc1 = __builtin_amdgcn_mfma_f32_16x16x32_bf16(A2, B0, acc1, 0, 0, 0);
                acc1 = __builtin_amdgcn_mfma_f32_16x16x32_bf16(A3, B1, acc1, 0, 0, 0);
                int code = cb + ct * 16 + n15;
#pragma unroll
                for (int r = 0; r < 4; ++r) {
                    float d0 = fmaf(-2.f, acc0[r], en);
                    if (d0 <= thr0[r]) {
                        int pos = atomicAdd(&ccnt[tb0 + r], 1);
                        if (pos < CAP) cand[tb0 + r][pos] = code;
                    }
                    float d1 = fmaf(-2.f, acc1[r], en);
                    if (d1 <= thr1[r]) {
                        int pos = atomicAdd(&ccnt[tb1 + r], 1);
                        if (pos < CAP) cand[tb1 + r][pos] = code;
                    }
                }
            }
        }

        if (have_next) {
            // safe: ebl[cur^1] was last read in phase p-1, sealed by its barrier
            STAGE_WRITE(cur ^ 1)
            __syncthreads();
            cur ^= 1;
        }
        // p==7: no stage, no flip, no barrier (chunk 7 reused; thresholds wave-local)
    }
    __syncthreads();   // pass-2 cand/ccnt visible

    // ---- exact fp32 rescore of candidates (frozen arithmetic; zrow in regs) ----
    if (tid < MTOK) {
        float zr[64];
#pragma unroll
        for (int c = 0; c < 64; ++c) zr[c] = zG[(size_t)c * SP + tid];
        int cnt = ccnt[tid];
        float best = 3.4e38f;
        int bi = 0;
        if (cnt <= CAP) {
            for (int j = 0; j < cnt; ++j) {
                int c = cand[tid][j];
                float d = exact_dist_r(zr, emb, enorm, c);
                if (d < best || (d == best && c < bi)) { best = d; bi = c; }
            }
        } else {   // overflow fallback (rare): exact scan, ascending
            for (int c = 0; c < KC; ++c) {
                float d = exact_dist_r(zr, emb, enorm, c);
                if (d < best) { best = d; bi = c; }
            }
        }
        fi[tid] = bi;
        out[OFF_IDX + t0 + tid] = (float)bi;   // coalesced
        atomicAdd(&hist[bi], 1);
    }
    __syncthreads();

    // ---- z_q epilogue: z + (e[code] - z), coalesced per channel ----
#pragma unroll
    for (int rep = 0; rep < 32; ++rep) {
        int idx = tid + rep * 256;   // 0..8191
        int c = idx >> 7;
        int t = idx & 127;
        int code = fi[t];
        float ev = emb[(size_t)code * CH + c];   // L1/L2-hot gather
        float zv = zG[(size_t)c * SP + t];
        out[OFF_ZQ + ((size_t)bb * CH + c) * SP + s0 + t] = zv + (ev - zv);
    }

    // ---- z statistics at tail: two 64-token halves, partial-sum structure
    //      bitwise identical to prior rounds (same values, same order) ----
    float* zs = reinterpret_cast<float*>(cand);   // 2048 B needed <= 3072 B
#pragma unroll
    for (int h = 0; h < 2; ++h) {
        const int c = tid >> 2, qq = tid & 3;
        float s1 = 0.f, s2 = 0.f;
#pragma unroll
        for (int tt = 0; tt < 16; ++tt) {
            float v = zG[(size_t)c * SP + h * 64 + qq * 16 + tt];
            s1 += v;
            s2 = fmaf(v, v, s2);
        }
        zs[tid] = s1;
        zs[256 + tid] = s2;
        __syncthreads();
        if (tid < 64) {
            float a = zs[4 * tid] + zs[4 * tid + 1] + zs[4 * tid + 2] + zs[4 * tid + 3];
            atomicAdd(&sum_zc[tid], a);
            float bsum = zs[256 + 4 * tid] + zs[256 + 4 * tid + 1]
                       + zs[256 + 4 * tid + 2] + zs[256 + 4 * tid + 3];
            for (int off = 32; off; off >>= 1) bsum += __shfl_down(bsum, off);
            if (tid == 0) atomicAdd(&sums[0], bsum);
        }
        __syncthreads();
    }
#undef STAGE_LOAD
#undef STAGE_WRITE
}

__global__ __launch_bounds__(1024) void finalize(const int* __restrict__ hist,
                                                 const float* __restrict__ sums,
                                                 const float* __restrict__ sum_zc,
                                                 const float* __restrict__ sum_ec,
                                                 float* __restrict__ out) {
    __shared__ float red[1024];
    int k = threadIdx.x;
    float p = (float)hist[k] * (1.0f / (float)NTOK);
    red[k] = p * logf(p + 1e-10f);
    __syncthreads();
    for (int off = 512; off; off >>= 1) {
        if (k < off) red[k] += red[k + off];
        __syncthreads();
    }
    if (k == 0) {
        out[OFF_PERP] = expf(-red[0]);
        out[OFF_LOSS] = 0.f;
        double dot = 0.0;
        for (int c = 0; c < CH; ++c) dot += (double)sum_zc[c] * (double)sum_ec[c];
        double mean = ((double)KC * (double)sums[0] + (double)NTOK * (double)sums[1] - 2.0 * dot)
                      / ((double)NTOK * (double)KC);
        out[OFF_MEAN] = (float)mean;
    }
}

extern "C" void kernel_launch(void* const* d_in, const int* in_sizes, int n_in,
                              void* d_out, int out_size, void* d_ws, size_t ws_size,
                              hipStream_t stream) {
    const float* z   = (const float*)d_in[0];
    const float* emb = (const float*)d_in[1];
    float* out = (float*)d_out;

    int*            hist   = (int*)d_ws;
    float*          sums   = (float*)d_ws + 1024;   // [0]=sum_z2 [1]=sum_e2
    float*          sum_zc = (float*)d_ws + 1026;
    float*          sum_ec = (float*)d_ws + 1090;
    float*          enorm  = (float*)d_ws + 1154;
    unsigned short* eb     = (unsigned short*)((int*)d_ws + 4096);  // 128 KB bf16 table

    prep<<<13, 256, 0, stream>>>(emb, hist, sums, sum_zc, sum_ec, enorm, eb);
    vq_main<<<NTOK / MTOK, 256, 0, stream>>>(z, emb, eb, enorm, out, hist, sums, sum_zc);
    finalize<<<1, 1024, 0, stream>>>(hist, sums, sum_zc, sum_ec, out);
}

// Round 3
// 546.323 us; speedup vs baseline: 1.3012x; 1.3012x over previous
//
#include <hip/hip_runtime.h>

// Problem constants (z: [4, 64, 32, 32, 32] f32, embedding: [1024, 64] f32)
#define CH     64
#define KC     1024
#define SP     32768              // 32*32*32
#define NBATCH 4
#define NTOK   (NBATCH * SP)      // 131072
#define MTOK   64                 // tokens per block
#define SZZ    68                 // zl row stride (floats)
#define ECH    128                // codes per LDS chunk (8 chunks)
#define CAP    8                  // candidate slots per token (overflow -> exact scan)
#define MARGIN 3.0f               // > 2*eps, eps = max |d_bf16 - d_fp32| (~0.9)

// d_out flat layout (all float32): z_q, loss, perplexity, indices, mean(dist)
#define OFF_ZQ   0
#define OFF_LOSS (NBATCH * CH * SP)      // 8388608
#define OFF_PERP (OFF_LOSS + 1)
#define OFF_IDX  (OFF_PERP + 1)          // 8388610
#define OFF_MEAN (OFF_IDX + NTOK)        // 8519682

// workspace layout (32-bit words)
// [0,1024)      int   hist
// [1024]        float sum_z2
// [1025]        float sum_e2
// [1026,1090)   float sum_zc[64]
// [1090,1154)   float sum_ec[64]
// [1154,2178)   float enorm[1024]
// [4096,20480)  ushort eb[1024*64]  (bf16 embedding table, 128 KB, L2-resident)

typedef __attribute__((ext_vector_type(8))) short  s16x8;   // 8 bf16 (4 VGPRs)
typedef __attribute__((ext_vector_type(4))) float  f32x4;

__device__ __forceinline__ unsigned short f2bf(float f) {   // RNE, deterministic
    unsigned int u = __float_as_uint(f);
    return (unsigned short)((u + 0x7fffu + ((u >> 16) & 1u)) >> 16);
}

// frozen exact fp32 distance (bitwise identical to round 0: stride-4
// fmaf chains ascending j, combine nrm - 2*((a0+a1)+(a2+a3)))
__device__ __forceinline__ float exact_dist(const float* zrow,
                                            const float* __restrict__ emb,
                                            const float* enl, int c) {
    const float4* er = (const float4*)(emb + (size_t)c * CH);
    float a0 = 0.f, a1 = 0.f, a2 = 0.f, a3 = 0.f;
#pragma unroll
    for (int j = 0; j < 16; ++j) {
        float4 e4 = er[j];
        a0 = fmaf(zrow[4 * j + 0], e4.x, a0);
        a1 = fmaf(zrow[4 * j + 1], e4.y, a1);
        a2 = fmaf(zrow[4 * j + 2], e4.z, a2);
        a3 = fmaf(zrow[4 * j + 3], e4.w, a3);
    }
    return enl[c] - 2.f * ((a0 + a1) + (a2 + a3));
}

// prep: blocks 0-3 enorm, block 4 col-stats + zero sums, 5-8 zero hist,
// 9-12 fp32->bf16 embedding table. (unchanged from round 0)
__global__ __launch_bounds__(256) void prep(const float* __restrict__ e,
                                            int* __restrict__ hist,
                                            float* __restrict__ sums,
                                            float* __restrict__ sum_zc,
                                            float* __restrict__ sum_ec,
                                            float* __restrict__ enorm,
                                            unsigned short* __restrict__ eb) {
    const int tid = threadIdx.x;
    const int bk = blockIdx.x;
    if (bk < 4) {
        int k = bk * 256 + tid;
        const float4* row = (const float4*)(e + (size_t)k * CH);
        float n = 0.f;
#pragma unroll
        for (int j = 0; j < CH / 4; ++j) {
            float4 v = row[j];
            n += v.x * v.x + v.y * v.y + v.z * v.z + v.w * v.w;
        }
        enorm[k] = n;
    } else if (bk == 4) {
        if (tid == 0) sums[0] = 0.f;
        if (tid < 64) sum_zc[tid] = 0.f;
        __shared__ float ls1[256];
        __shared__ float r2[4];
        int c = tid & 63;
        int strip = tid >> 6;
        float s1 = 0.f, s2 = 0.f;
        for (int k = strip * 256; k < strip * 256 + 256; ++k) {
            float v = e[k * CH + c];
            s1 += v;
            s2 = fmaf(v, v, s2);
        }
        ls1[tid] = s1;
        for (int off = 32; off; off >>= 1) s2 += __shfl_down(s2, off);
        if ((tid & 63) == 0) r2[tid >> 6] = s2;
        __syncthreads();
        if (strip == 0) sum_ec[c] = ls1[c] + ls1[64 + c] + ls1[128 + c] + ls1[192 + c];
        if (tid == 0) sums[1] = r2[0] + r2[1] + r2[2] + r2[3];
    } else if (bk < 9) {
        hist[(bk - 5) * 256 + tid] = 0;
    } else {
        int base = (bk - 9) * 16384;
        for (int j = 0; j < 64; ++j) {
            int i = base + tid + j * 256;
            eb[i] = f2bf(e[i]);
        }
    }
}

// main: round-0 structure (z + eb chunk in LDS) with
//  - ECH=128, un-padded ebl rows + XOR granule swizzle (g^=row&7)
//  - register-prefetch staging (load next chunk during current compute)
//  - LDS 40704 B -> 4 blocks/CU
// Decision logic and all value-producing arithmetic frozen (absmax 0).
__global__ __launch_bounds__(256, 4) void vq_main(const float* __restrict__ z,
                                                  const float* __restrict__ emb,
                                                  const unsigned short* __restrict__ eb,
                                                  const float* __restrict__ enorm,
                                                  float* __restrict__ out,
                                                  int* __restrict__ hist,
                                                  float* __restrict__ sums,
                                                  float* __restrict__ sum_zc) {
    __shared__ float zl[MTOK * SZZ];                        // 17408 B fp32 z, token-major
    __shared__ __align__(16) unsigned short ebl[ECH * 64];  // 16384 B bf16 chunk, swizzled
    __shared__ float enorm_l[KC];                           // 4096 B
    __shared__ float dmin_l[MTOK];                          // 256 B
    __shared__ int   cand[MTOK][CAP];                       // 2048 B (zs-aliased at tail)
    __shared__ int   ccnt[MTOK];                            // 256 B
    __shared__ int   fi[MTOK];                              // 256 B

    const int tid = threadIdx.x;
    const int w = tid >> 6;             // wave 0..3
    const int lane = tid & 63;
    const int n15 = lane & 15;
    const int q = lane >> 4;            // 0..3
    const int t0 = blockIdx.x * MTOK;   // grid = 2048
    const int bb = t0 >> 15;
    const int s0 = t0 & (SP - 1);

    // staging decomposition: granule g = tid&7 (const), rows sr0 + {0,32,64,96}
    const int sg  = tid & 7;
    const int sr0 = tid >> 3;                 // 0..31
    const int sgd = sg ^ (sr0 & 7);           // swizzled dest granule (const per thread)
    float4 g0, g1, g2, g3;
#define STAGE_LOAD(cb)                                                      \
    {                                                                       \
        g0 = ((const float4*)(eb + (size_t)((cb) + sr0) * CH))[sg];         \
        g1 = ((const float4*)(eb + (size_t)((cb) + sr0 + 32) * CH))[sg];    \
        g2 = ((const float4*)(eb + (size_t)((cb) + sr0 + 64) * CH))[sg];    \
        g3 = ((const float4*)(eb + (size_t)((cb) + sr0 + 96) * CH))[sg];    \
    }
#define STAGE_WRITE()                                                       \
    {                                                                       \
        ((float4*)&ebl[(size_t)sr0 * 64])[sgd] = g0;                        \
        ((float4*)&ebl[(size_t)(sr0 + 32) * 64])[sgd] = g1;                 \
        ((float4*)&ebl[(size_t)(sr0 + 64) * 64])[sgd] = g2;                 \
        ((float4*)&ebl[(size_t)(sr0 + 96) * 64])[sgd] = g3;                 \
    }

    // ---- stage z tile token-major + enorm + ccnt + chunk 0 (round-0 prologue) ----
    {
        const float* zbase = z + ((size_t)bb * CH) * SP + s0;
#pragma unroll
        for (int j = 0; j < 4; ++j) {
            int idx = tid + j * 256;        // 0..1023
            int c = idx >> 4;
            int tq = idx & 15;
            float4 v = *(const float4*)(zbase + (size_t)c * SP + tq * 4);
            zl[(4 * tq + 0) * SZZ + c] = v.x;
            zl[(4 * tq + 1) * SZZ + c] = v.y;
            zl[(4 * tq + 2) * SZZ + c] = v.z;
            zl[(4 * tq + 3) * SZZ + c] = v.w;
        }
#pragma unroll
        for (int j = 0; j < 4; ++j) enorm_l[tid + j * 256] = enorm[tid + j * 256];
        if (tid < MTOK) ccnt[tid] = 0;
        STAGE_LOAD(0)
        STAGE_WRITE()
    }
    __syncthreads();

    // ---- persistent A fragments (round-0 layout, verified) ----
    s16x8 A0, A1;
    {
        const float* zrow = &zl[(w * 16 + n15) * SZZ];
        float4 za = *(const float4*)(zrow + q * 8);
        float4 zb = *(const float4*)(zrow + q * 8 + 4);
        float4 zc = *(const float4*)(zrow + 32 + q * 8);
        float4 zd = *(const float4*)(zrow + 32 + q * 8 + 4);
        A0[0] = (short)f2bf(za.x); A0[1] = (short)f2bf(za.y);
        A0[2] = (short)f2bf(za.z); A0[3] = (short)f2bf(za.w);
        A0[4] = (short)f2bf(zb.x); A0[5] = (short)f2bf(zb.y);
        A0[6] = (short)f2bf(zb.z); A0[7] = (short)f2bf(zb.w);
        A1[0] = (short)f2bf(zc.x); A1[1] = (short)f2bf(zc.y);
        A1[2] = (short)f2bf(zc.z); A1[3] = (short)f2bf(zc.w);
        A1[4] = (short)f2bf(zd.x); A1[5] = (short)f2bf(zd.y);
        A1[6] = (short)f2bf(zd.z); A1[7] = (short)f2bf(zd.w);
    }
    const int gsw = q ^ (n15 & 7);     // B0 read granule after swizzle (row&7 == n15&7)

    // ---- pass 1: per-token min of d_bf; prefetch next chunk during compute ----
    float bmin[4] = {3.4e38f, 3.4e38f, 3.4e38f, 3.4e38f};
    for (int p = 0; p < 8; ++p) {
        if (p < 7) STAGE_LOAD((p + 1) * ECH)          // in regs during compute
        const int cb = p * ECH;
#pragma unroll
        for (int ct = 0; ct < 8; ++ct) {
            const s16x8* rowp = (const s16x8*)&ebl[(size_t)(ct * 16 + n15) * 64];
            s16x8 B0 = rowp[gsw];
            s16x8 B1 = rowp[gsw ^ 4];
            f32x4 acc = {0.f, 0.f, 0.f, 0.f};
            acc = __builtin_amdgcn_mfma_f32_16x16x32_bf16(A0, B0, acc, 0, 0, 0);
            acc = __builtin_amdgcn_mfma_f32_16x16x32_bf16(A1, B1, acc, 0, 0, 0);
            float en = enorm_l[cb + ct * 16 + n15];
#pragma unroll
            for (int r = 0; r < 4; ++r) {
                float d = fmaf(-2.f, acc[r], en);
                bmin[r] = fminf(bmin[r], d);
            }
        }
        if (p == 7) {
#pragma unroll
            for (int off = 1; off < 16; off <<= 1)
#pragma unroll
                for (int r = 0; r < 4; ++r)
                    bmin[r] = fminf(bmin[r], __shfl_xor(bmin[r], off));
            if (n15 == 0)
#pragma unroll
                for (int r = 0; r < 4; ++r) dmin_l[w * 16 + 4 * q + r] = bmin[r];
        }
        __syncthreads();                               // seals ebl reads (+dmin at p==7)
        if (p < 7) {
            STAGE_WRITE()
            __syncthreads();
        }
    }

    // ---- pass 2: identical compute, collect candidates within margin.
    //      chunk order 7,0..6: chunk 7 still resident -> no restage ----
    float thr[4];
#pragma unroll
    for (int r = 0; r < 4; ++r) thr[r] = dmin_l[w * 16 + 4 * q + r] + MARGIN;
    for (int p = 0; p < 8; ++p) {
        const int chunk = (p == 0) ? 7 : (p - 1);
        if (p < 7) STAGE_LOAD(p * ECH)                 // next chunk = p
        const int cb = chunk * ECH;
#pragma unroll
        for (int ct = 0; ct < 8; ++ct) {
            const s16x8* rowp = (const s16x8*)&ebl[(size_t)(ct * 16 + n15) * 64];
            s16x8 B0 = rowp[gsw];
            s16x8 B1 = rowp[gsw ^ 4];
            f32x4 acc = {0.f, 0.f, 0.f, 0.f};
            acc = __builtin_amdgcn_mfma_f32_16x16x32_bf16(A0, B0, acc, 0, 0, 0);
            acc = __builtin_amdgcn_mfma_f32_16x16x32_bf16(A1, B1, acc, 0, 0, 0);
            float en = enorm_l[cb + ct * 16 + n15];
#pragma unroll
            for (int r = 0; r < 4; ++r) {
                float d = fmaf(-2.f, acc[r], en);
                if (d <= thr[r]) {
                    int t = w * 16 + 4 * q + r;
                    int pos = atomicAdd(&ccnt[t], 1);
                    if (pos < CAP) cand[t][pos] = cb + ct * 16 + n15;
                }
            }
        }
        __syncthreads();
        if (p < 7) {
            STAGE_WRITE()
            __syncthreads();
        }
    }

    // ---- exact fp32 rescore of candidates (frozen arithmetic) ----
    if (tid < MTOK) {
        int t = tid;
        const float* zrow = &zl[t * SZZ];
        int cnt = ccnt[t];
        float best = 3.4e38f;
        int bi = 0;
        if (cnt <= CAP) {
            for (int j = 0; j < cnt; ++j) {
                int c = cand[t][j];
                float d = exact_dist(zrow, emb, enorm_l, c);
                if (d < best || (d == best && c < bi)) { best = d; bi = c; }
            }
        } else {   // overflow fallback (rare): exact scan, ascending
            for (int c = 0; c < KC; ++c) {
                float d = exact_dist(zrow, emb, enorm_l, c);
                if (d < best) { best = d; bi = c; }
            }
        }
        fi[t] = bi;
        out[OFF_IDX + t0 + t] = (float)bi;   // coalesced
        atomicAdd(&hist[bi], 1);
    }
    __syncthreads();

    // ---- z_q epilogue: z + (e[code] - z), coalesced per channel ----
#pragma unroll
    for (int j = 0; j < 16; ++j) {
        int idx = tid + j * 256;   // 0..4095
        int c = idx >> 6;
        int t = idx & 63;
        int code = fi[t];
        float ev = emb[(size_t)code * CH + c];   // L1/L2-hot gather
        float zv = zl[t * SZZ + c];
        out[OFF_ZQ + ((size_t)bb * CH + c) * SP + s0 + t] = zv + (ev - zv);
    }

    // ---- z statistics at kernel tail (zs aliased onto cand; 2048 B exact) ----
    {
        float* zs1 = reinterpret_cast<float*>(cand);
        float* zs2 = zs1 + 256;
        int c = tid >> 2, qq = tid & 3;
        float s1 = 0.f, s2 = 0.f;
        for (int tt = 0; tt < 16; ++tt) {
            float v = zl[(qq * 16 + tt) * SZZ + c];
            s1 += v;
            s2 = fmaf(v, v, s2);
        }
        zs1[tid] = s1;
        zs2[tid] = s2;
        __syncthreads();
        if (tid < 64) {
            float a = zs1[4 * tid] + zs1[4 * tid + 1] + zs1[4 * tid + 2] + zs1[4 * tid + 3];
            atomicAdd(&sum_zc[tid], a);
            float bsum = zs2[4 * tid] + zs2[4 * tid + 1] + zs2[4 * tid + 2] + zs2[4 * tid + 3];
            for (int off = 32; off; off >>= 1) bsum += __shfl_down(bsum, off);
            if (tid == 0) atomicAdd(&sums[0], bsum);
        }
    }
#undef STAGE_LOAD
#undef STAGE_WRITE
}

__global__ __launch_bounds__(1024) void finalize(const int* __restrict__ hist,
                                                 const float* __restrict__ sums,
                                                 const float* __restrict__ sum_zc,
                                                 const float* __restrict__ sum_ec,
                                                 float* __restrict__ out) {
    __shared__ float red[1024];
    int k = threadIdx.x;
    float p = (float)hist[k] * (1.0f / (float)NTOK);
    red[k] = p * logf(p + 1e-10f);
    __syncthreads();
    for (int off = 512; off; off >>= 1) {
        if (k < off) red[k] += red[k + off];
        __syncthreads();
    }
    if (k == 0) {
        out[OFF_PERP] = expf(-red[0]);
        out[OFF_LOSS] = 0.f;
        double dot = 0.0;
        for (int c = 0; c < CH; ++c) dot += (double)sum_zc[c] * (double)sum_ec[c];
        double mean = ((double)KC * (double)sums[0] + (double)NTOK * (double)sums[1] - 2.0 * dot)
                      / ((double)NTOK * (double)KC);
        out[OFF_MEAN] = (float)mean;
    }
}

extern "C" void kernel_launch(void* const* d_in, const int* in_sizes, int n_in,
                              void* d_out, int out_size, void* d_ws, size_t ws_size,
                              hipStream_t stream) {
    const float* z   = (const float*)d_in[0];
    const float* emb = (const float*)d_in[1];
    float* out = (float*)d_out;

    int*            hist   = (int*)d_ws;
    float*          sums   = (float*)d_ws + 1024;   // [0]=sum_z2 [1]=sum_e2
    float*          sum_zc = (float*)d_ws + 1026;
    float*          sum_ec = (float*)d_ws + 1090;
    float*          enorm  = (float*)d_ws + 1154;
    unsigned short* eb     = (unsigned short*)((int*)d_ws + 4096);  // 128 KB bf16 table

    prep<<<13, 256, 0, stream>>>(emb, hist, sums, sum_zc, sum_ec, enorm, eb);
    vq_main<<<NTOK / MTOK, 256, 0, stream>>>(z, emb, eb, enorm, out, hist, sums, sum_zc);
    finalize<<<1, 1024, 0, stream>>>(hist, sums, sum_zc, sum_ec, out);
}